// Round 11
// baseline (280.171 us; speedup 1.0000x reference)
//
#include <hip/hip_runtime.h>
#include <hip/hip_bf16.h>

#define NN 100000
#define NE 1600000
#define DD 128

#define ASHIFT 8            // bucket = dst >> 8 (256-node span)
#define NSPAN  256
#define BK     391          // ceil(100000/256)
#define BCAP   4608         // per-bucket capacity (mean 4092, +8 sigma)
#define EPB    8192         // edges per binning block (196 blocks -> low gcur contention)
#define NAB    196          // ceil(NE/EPB)
#define TFH    1563         // tofeat blocks per half: ceil(800000/512)
#define HELEM  800000       // elem-groups (of 8) per tofeat half
#define PWB    16           // prepw blocks at 512 thr (8192 threads)
#define CGRID  1024         // combine grid (512-thread blocks)
#define GPB    782          // gather blocks per (panel,parity): ceil(50000/64)

typedef __attribute__((ext_vector_type(8))) short bf16x8;
typedef __attribute__((ext_vector_type(4))) float f32x4;
typedef __attribute__((ext_vector_type(2))) float f32x2;

__device__ inline unsigned short f2bf(float f) {          // RNE float->bf16
    unsigned u = __builtin_bit_cast(unsigned, f);
    u += 0x7fff + ((u >> 16) & 1);
    return (unsigned short)(u >> 16);
}
__device__ inline float bf2f(unsigned short h) {
    return __builtin_bit_cast(float, (unsigned)h << 16);
}

// async 16B global->LDS (zero VGPR data path; HW adds lane*16 to the LDS base)
__device__ inline void gload16(const void* g, void* l) {
    __builtin_amdgcn_global_load_lds(
        (const __attribute__((address_space(1))) unsigned int*)g,
        (__attribute__((address_space(3))) unsigned int*)l, 16, 0, 0);
}

// ---- shared tofeat body: convert elem-groups [h*HELEM, h*HELEM+HELEM) ----
// fp8 output is PANEL-MAJOR: out8[panel][node][32], panel = colgroup>>2.
// (32-col panels of 3.2MB each -> one panel fits a 4MB XCD L2; row-major
//  64B lines would span two panels and defeat the gather working-set cut.)
__device__ inline void tofeat_body(int half, int blk, int t,
                                   const float* __restrict__ in,
                                   unsigned short* __restrict__ outb,
                                   unsigned char* __restrict__ out8) {
    const size_t local = (size_t)blk * 512 + t;
    if (local >= HELEM) return;
    const size_t i = (size_t)half * HELEM + local;
    const float4 a = *(const float4*)&in[i * 8];
    const float4 b = *(const float4*)&in[i * 8 + 4];
    unsigned short o[8] = {f2bf(a.x), f2bf(a.y), f2bf(a.z), f2bf(a.w),
                           f2bf(b.x), f2bf(b.y), f2bf(b.z), f2bf(b.w)};
    *(bf16x8*)&outb[i * 8] = *(bf16x8*)o;
    unsigned e0 = 0, e1 = 0;
    e0 = __builtin_amdgcn_cvt_pk_fp8_f32(a.x, a.y, e0, false);
    e0 = __builtin_amdgcn_cvt_pk_fp8_f32(a.z, a.w, e0, true);
    e1 = __builtin_amdgcn_cvt_pk_fp8_f32(b.x, b.y, e1, false);
    e1 = __builtin_amdgcn_cvt_pk_fp8_f32(b.z, b.w, e1, true);
    uint2 p = {e0, e1};
    const size_t n = i >> 4;                 // node
    const int    c = (int)(i & 15);          // col-group of 8
    const int    pn = c >> 2;                // panel
    const int    off = (c & 3) * 8;          // byte offset in 32B panel row
    *(uint2*)&out8[((size_t)pn * NN + n) * 32 + off] = p;
}

// ---------------- launch 1: binning + tofeat(half 0) + prepw ----------------
// pairs entry: (local_dst << 17) | src   (src < 2^17, local < 2^8)
__global__ __launch_bounds__(512) void fusedA2(const int* __restrict__ src,
                                               const int* __restrict__ dst,
                                               int* __restrict__ gcur,
                                               int* __restrict__ pairs,
                                               const float* __restrict__ in,
                                               unsigned short* __restrict__ outb,
                                               unsigned char* __restrict__ out8,
                                               const float* __restrict__ Wl1,
                                               const float* __restrict__ Wr1,
                                               const float* __restrict__ Wl2,
                                               const float* __restrict__ Wr2,
                                               unsigned short* __restrict__ wsb) {
    __shared__ int hist[BK];
    __shared__ int gbase[BK];
    __shared__ int lcur[BK];
    const int t = threadIdx.x;

    if (blockIdx.x >= NAB + TFH) {
        // ---- prepw part ----
        const int tid = (blockIdx.x - NAB - TFH) * 512 + t;   // 8192 total
        const int mat = tid >> 11;
        const int ko  = (tid >> 7) & 15;
        const int j   = tid & 127;
        const float* W = (mat == 0) ? Wl1 : (mat == 1) ? Wr1 : (mat == 2) ? Wl2 : Wr2;
        const float4 w0 = *(const float4*)&W[(size_t)j * DD + ko * 8];
        const float4 w1 = *(const float4*)&W[(size_t)j * DD + ko * 8 + 4];
        unsigned short o[8] = {f2bf(w0.x), f2bf(w0.y), f2bf(w0.z), f2bf(w0.w),
                               f2bf(w1.x), f2bf(w1.y), f2bf(w1.z), f2bf(w1.w)};
        *(bf16x8*)&wsb[(size_t)tid * 8] = *(bf16x8*)o;
        return;
    }
    if (blockIdx.x >= NAB) {
        tofeat_body(0, blockIdx.x - NAB, t, in, outb, out8);
        return;
    }

    // ---- binning part ----
    const int e0 = blockIdx.x * EPB;
    int dcache[16];
    #pragma unroll
    for (int k = 0; k < 16; ++k) {
        const int e = e0 + t + k * 512;
        dcache[k] = (e < NE) ? dst[e] : -1;
    }

    for (int i = t; i < BK; i += 512) hist[i] = 0;
    __syncthreads();
    #pragma unroll
    for (int k = 0; k < 16; ++k)
        if (dcache[k] >= 0) atomicAdd(&hist[dcache[k] >> ASHIFT], 1);
    __syncthreads();
    for (int i = t; i < BK; i += 512) {
        int c = hist[i];
        gbase[i] = i * BCAP + (c ? atomicAdd(&gcur[i], c) : 0);  // block-private run
        lcur[i] = 0;
    }
    __syncthreads();
    #pragma unroll
    for (int k = 0; k < 16; ++k) {
        const int e = e0 + t + k * 512;
        const int d = dcache[k];
        if (d >= 0) {
            const int b = d >> ASHIFT;
            const int r = atomicAdd(&lcur[b], 1);
            pairs[gbase[b] + r] = ((d & (NSPAN - 1)) << 17) | src[e];
        }
    }
}

// ---------------- launch 2: bucketB (CSR finalize) + tofeat(half 1) --------
__global__ __launch_bounds__(512) void fusedB2(const int* __restrict__ pairs,
                                               const int* __restrict__ gcur,
                                               int* __restrict__ cnt,
                                               int* __restrict__ rowoff,
                                               int* __restrict__ csr,
                                               const float* __restrict__ in,
                                               unsigned short* __restrict__ outb,
                                               unsigned char* __restrict__ out8) {
    __shared__ int bs[512];
    __shared__ int hist[NSPAN];
    __shared__ int scanbuf[NSPAN];
    const int t = threadIdx.x;

    if (blockIdx.x >= BK) {
        tofeat_body(1, blockIdx.x - BK, t, in, outb, out8);
        return;
    }

    const int b = blockIdx.x;
    int v = (t < BK) ? gcur[t] : 0;
    bs[t] = v;
    __syncthreads();
    #pragma unroll
    for (int d = 1; d < 512; d <<= 1) {
        int u = (t >= d) ? bs[t - d] : 0;
        __syncthreads();
        bs[t] += u;
        __syncthreads();
    }
    const int sz   = gcur[b];
    const int base = bs[b] - sz;          // exclusive prefix

    const int n0    = b << ASHIFT;
    const int nodeN = min(NSPAN, NN - n0);
    const int* ep   = &pairs[(size_t)b * BCAP];

    for (int i = t; i < NSPAN; i += 512) hist[i] = 0;
    __syncthreads();
    for (int i = t; i < sz; i += 512) atomicAdd(&hist[((unsigned)ep[i]) >> 17], 1);
    __syncthreads();
    for (int i = t; i < nodeN; i += 512) cnt[n0 + i] = hist[i];
    for (int i = t; i < NSPAN; i += 512) scanbuf[i] = hist[i];
    __syncthreads();
    #pragma unroll
    for (int d = 1; d < NSPAN; d <<= 1) {
        int v0 = (t >= d && t < NSPAN) ? scanbuf[t - d] : 0;
        __syncthreads();
        if (t < NSPAN) scanbuf[t] += v0;
        __syncthreads();
    }
    for (int i = t; i < NSPAN; i += 512) {
        int excl = scanbuf[i] - hist[i];
        if (i < nodeN) rowoff[n0 + i] = base + excl;
        hist[i] = excl;                     // reuse as cursor
    }
    if (b == BK - 1 && t == 0) rowoff[NN] = NE;
    __syncthreads();
    for (int i = t; i < sz; i += 512) {
        int p = ep[i];
        int r = atomicAdd(&hist[((unsigned)p) >> 17], 1);
        csr[base + r] = p & 0x1FFFF;        // block-private ~16KB window
    }
}

// ---------------- gather mean, panel-split + XCD-pinned ----------------
// The fp8 table (12.8MB) thrashes a 4MB XCD L2 -> random reads served by L3
// at ~5-6 TB/s (the old gather's floor). Fix: 4 panels of 32 cols (3.2MB,
// panel-major) and key the panel on blockIdx&7 (the XCD round-robin
// heuristic): each XCD touches ONE panel -> L2-resident after warmup.
// 4 lanes/node x 8B, same 8-deep unroll and a0/a1 order -> bitwise-identical.
// mean stays row-major: pass p writes bytes [64p,64p+64) of the 256B row
// (full-line stores, no amplification).
__device__ inline void accum8(float* a, uint2 u) {
    f32x2 p;
    p = __builtin_amdgcn_cvt_pk_f32_fp8(u.x, false); a[0] += p.x; a[1] += p.y;
    p = __builtin_amdgcn_cvt_pk_f32_fp8(u.x, true);  a[2] += p.x; a[3] += p.y;
    p = __builtin_amdgcn_cvt_pk_f32_fp8(u.y, false); a[4] += p.x; a[5] += p.y;
    p = __builtin_amdgcn_cvt_pk_f32_fp8(u.y, true);  a[6] += p.x; a[7] += p.y;
}

__global__ __launch_bounds__(256) void gather_panel(const unsigned char* __restrict__ feat,
                                                    const int* __restrict__ rowoff,
                                                    const int* __restrict__ csr,
                                                    const int* __restrict__ cnt,
                                                    unsigned short* __restrict__ mean) {
    const int b      = blockIdx.x;
    const int xcd    = b & 7;              // XCD round-robin heuristic key
    const int panel  = xcd >> 1;           // 2 XCDs per panel
    const int parity = xcd & 1;            // node half
    const int local  = b >> 3;             // 0..GPB-1
    const int t = threadIdx.x;
    const int node = parity * 50000 + local * 64 + (t >> 2);
    const int limit = parity ? NN : 50000;
    if (node >= limit) return;
    const int l8 = (t & 3) * 8;            // byte offset in 32B panel row
    const unsigned char* fp = feat + (size_t)panel * NN * 32;

    const int beg = rowoff[node], end = rowoff[node + 1];
    float a0[8] = {0, 0, 0, 0, 0, 0, 0, 0};
    float a1[8] = {0, 0, 0, 0, 0, 0, 0, 0};
    int j = beg;
    for (; j + 7 < end; j += 8) {
        int s0 = csr[j],     s1 = csr[j + 1], s2 = csr[j + 2], s3 = csr[j + 3];
        int s4 = csr[j + 4], s5 = csr[j + 5], s6 = csr[j + 6], s7 = csr[j + 7];
        uint2 u0 = *(const uint2*)&fp[(size_t)s0 * 32 + l8];
        uint2 u1 = *(const uint2*)&fp[(size_t)s1 * 32 + l8];
        uint2 u2 = *(const uint2*)&fp[(size_t)s2 * 32 + l8];
        uint2 u3 = *(const uint2*)&fp[(size_t)s3 * 32 + l8];
        uint2 u4 = *(const uint2*)&fp[(size_t)s4 * 32 + l8];
        uint2 u5 = *(const uint2*)&fp[(size_t)s5 * 32 + l8];
        uint2 u6 = *(const uint2*)&fp[(size_t)s6 * 32 + l8];
        uint2 u7 = *(const uint2*)&fp[(size_t)s7 * 32 + l8];
        accum8(a0, u0); accum8(a1, u1); accum8(a0, u2); accum8(a1, u3);
        accum8(a0, u4); accum8(a1, u5); accum8(a0, u6); accum8(a1, u7);
    }
    for (; j + 3 < end; j += 4) {
        int s0 = csr[j], s1 = csr[j + 1], s2 = csr[j + 2], s3 = csr[j + 3];
        uint2 u0 = *(const uint2*)&fp[(size_t)s0 * 32 + l8];
        uint2 u1 = *(const uint2*)&fp[(size_t)s1 * 32 + l8];
        uint2 u2 = *(const uint2*)&fp[(size_t)s2 * 32 + l8];
        uint2 u3 = *(const uint2*)&fp[(size_t)s3 * 32 + l8];
        accum8(a0, u0); accum8(a1, u1); accum8(a0, u2); accum8(a1, u3);
    }
    for (; j < end; ++j) {
        int s0 = csr[j];
        uint2 u0 = *(const uint2*)&fp[(size_t)s0 * 32 + l8];
        accum8(a0, u0);
    }
    const float inv = 1.0f / fmaxf((float)cnt[node], 1.0f);
    unsigned short o[8];
    #pragma unroll
    for (int i = 0; i < 8; ++i) o[i] = f2bf((a0[i] + a1[i]) * inv);
    *(bf16x8*)&mean[(size_t)node * DD + panel * 32 + (t & 3) * 8] = *(bf16x8*)o;
}

// ---------------- combine via MFMA, LDS-staged A (m97 pattern) ----------------
// 512 thr = 8 waves; wave wv owns output column-tile jt = wv -> bfr is only
// 8 frags (32 VGPR), keeping the live set under the allocator's 85-reg
// occupancy step. A-tiles double-buffered in LDS via global_load_lds.
// out8 (layer-1 h fp8) is written PANEL-MAJOR to match gather_panel:
// panel = wv>>1, in-panel byte = (wv&1)*16 + m.
__global__ __launch_bounds__(512, 3) void combine_lds(
    const unsigned short* __restrict__ meanp, const unsigned short* __restrict__ selfp,
    const unsigned short* __restrict__ wsb,   // pre-converted bf16 fragments (64KB)
    const float* __restrict__ bias, void* __restrict__ outp,
    unsigned char* __restrict__ out8,         // optional fp8 copy (panel-major)
    int out_bf16, int do_relu)
{
    __shared__ unsigned short sAB[2][2][2048];   // [buf][mean/self][16 rows x 128] 16KB
    const int t = threadIdx.x;
    const int wv = t >> 6, lane = t & 63;
    const int m = lane & 15;
    const int q = lane >> 4;
    const int j0 = wv;                        // this wave's single jt column

    // staging role of this wave: region (mean/self) + kq slice
    const int sreg = wv >> 2;                 // 0 = mean, 1 = self
    const int skq  = wv & 3;
    const int soff = m * 256 + skq * 64 + q * 16;   // per-lane source byte offset

    // register-resident B fragments: [half][kq] — 8 frags = 32 VGPR
    bf16x8 bfr[2][4];
    #pragma unroll
    for (int h = 0; h < 2; ++h)
        #pragma unroll
        for (int kq = 0; kq < 4; ++kq)
            bfr[h][kq] = *(const bf16x8*)
                &wsb[((size_t)((h * 16 + kq * 4 + q) * 128) + j0 * 16 + m) * 8];

    const float bv = bias[j0 * 16 + m];

    const int NT = NN / 16;
    const int opan = wv >> 1;                 // out8 panel
    const int ooff = (wv & 1) * 16 + m;       // out8 in-panel byte offset

#define STAGE(BUF, TL)                                                        \
    {                                                                         \
        const char* base_ = sreg ? (const char*)selfp : (const char*)meanp;   \
        gload16(base_ + (size_t)(TL) * 4096 + soff,                           \
                (char*)&sAB[BUF][sreg][0] + skq * 1024);                      \
    }

    int tile = blockIdx.x;
    STAGE(0, tile)
    __syncthreads();                           // drains vmcnt(0): buf0 ready
    int cur = 0;

    for (; tile < NT; tile += CGRID) {
        const int nxt = tile + CGRID;
        if (nxt < NT) STAGE(cur ^ 1, nxt)      // async prefetch next tile

        f32x4 acc = (f32x4){0.f, 0.f, 0.f, 0.f};
        #pragma unroll
        for (int kq = 0; kq < 4; ++kq) {
            const bf16x8 am = *(const bf16x8*)&sAB[cur][0][kq * 512 + lane * 8];
            const bf16x8 as = *(const bf16x8*)&sAB[cur][1][kq * 512 + lane * 8];
            acc = __builtin_amdgcn_mfma_f32_16x16x32_bf16(am, bfr[0][kq], acc, 0, 0, 0);
            acc = __builtin_amdgcn_mfma_f32_16x16x32_bf16(as, bfr[1][kq], acc, 0, 0, 0);
        }

        const int col = j0 * 16 + m;
        #pragma unroll
        for (int r = 0; r < 4; ++r) {
            const size_t row = (size_t)tile * 16 + q * 4 + r;
            float v = acc[r] + bv;
            if (do_relu) v = fmaxf(v, 0.0f);
            if (out_bf16)
                ((unsigned short*)outp)[row * DD + col] = f2bf(v);
            else
                ((float*)outp)[row * DD + col] = v;
            if (out8) {
                unsigned p = __builtin_amdgcn_cvt_pk_fp8_f32(v, v, 0u, false);
                out8[((size_t)opan * NN + row) * 32 + ooff] = (unsigned char)p;
            }
        }

        __syncthreads();                       // drains next-tile loads; all
        cur ^= 1;                              // reads of cur complete
    }
#undef STAGE
}

extern "C" void kernel_launch(void* const* d_in, const int* in_sizes, int n_in,
                              void* d_out, int out_size, void* d_ws, size_t ws_size,
                              hipStream_t stream) {
    const float* x   = (const float*)d_in[0];
    const int*   ei  = (const int*)d_in[1];
    const float* Wl1 = (const float*)d_in[2];
    const float* Wr1 = (const float*)d_in[3];
    const float* b1  = (const float*)d_in[4];
    const float* Wl2 = (const float*)d_in[5];
    const float* Wr2 = (const float*)d_in[6];
    const float* b2  = (const float*)d_in[7];
    const int* src = ei;
    const int* dst = ei + NE;
    float* out = (float*)d_out;

    // workspace layout
    unsigned short* xb   = (unsigned short*)d_ws;              // NN*DD bf16 (25.6MB)
    unsigned short* mean = xb + (size_t)NN * DD;               // NN*DD bf16 (25.6MB)
    unsigned short* h    = mean + (size_t)NN * DD;             // NN*DD bf16 (25.6MB)
    unsigned char*  x8   = (unsigned char*)(h + (size_t)NN * DD); // 4 panels x NN x 32 (12.8MB)
    unsigned char*  h8   = x8 + (size_t)NN * DD;               // 4 panels x NN x 32 (12.8MB)
    int*  pairs  = (int*)(h8 + (size_t)NN * DD);               // BK*BCAP (7.2MB)
    int*  gcur   = pairs + (size_t)BK * BCAP;                  // BK
    int*  cnt    = gcur + BK;                                  // NN
    int*  rowoff = cnt + NN;                                   // NN+1
    int*  csr    = rowoff + NN + 1;                            // NE (6.4MB)
    uintptr_t wp = ((uintptr_t)(csr + NE) + 255) & ~(uintptr_t)255;
    unsigned short* wsb = (unsigned short*)wp;                 // 2 layers * 32768 bf16 (128KB)

    hipMemsetAsync(gcur, 0, BK * sizeof(int), stream);
    fusedA2<<<NAB + TFH + PWB, 512, 0, stream>>>(src, dst, gcur, pairs,
                                                 x, xb, x8,
                                                 Wl1, Wr1, Wl2, Wr2, wsb);
    fusedB2<<<BK + TFH, 512, 0, stream>>>(pairs, gcur, cnt, rowoff, csr, x, xb, x8);

    gather_panel<<<8 * GPB, 256, 0, stream>>>(x8, rowoff, csr, cnt, mean);
    combine_lds<<<CGRID, 512, 0, stream>>>(mean, xb, wsb, b1, h, h8, 1, 1);

    gather_panel<<<8 * GPB, 256, 0, stream>>>(h8, rowoff, csr, cnt, mean);
    combine_lds<<<CGRID, 512, 0, stream>>>(mean, h, wsb + 32768, b2, out, nullptr, 0, 0);
}

// Round 12
// 271.008 us; speedup vs baseline: 1.0338x; 1.0338x over previous
//
#include <hip/hip_runtime.h>
#include <hip/hip_bf16.h>

#define NN 100000
#define NE 1600000
#define DD 128

#define ASHIFT 8            // bucket = dst >> 8 (256-node span)
#define NSPAN  256
#define BK     391          // ceil(100000/256)
#define BCAP   4608         // per-bucket capacity (mean 4092, +8 sigma)
#define EPB    8192         // edges per binning block (196 blocks -> low gcur contention)
#define NAB    196          // ceil(NE/EPB)
#define TFH    1563         // tofeat blocks per half: ceil(800000/512)
#define HELEM  800000       // elem-groups (of 8) per tofeat half
#define PWB    16           // prepw blocks at 512 thr (8192 threads)
#define CGRID  1024         // combine grid (512-thread blocks)

typedef __attribute__((ext_vector_type(8))) short bf16x8;
typedef __attribute__((ext_vector_type(4))) float f32x4;
typedef __attribute__((ext_vector_type(2))) float f32x2;

__device__ inline unsigned short f2bf(float f) {          // RNE float->bf16
    unsigned u = __builtin_bit_cast(unsigned, f);
    u += 0x7fff + ((u >> 16) & 1);
    return (unsigned short)(u >> 16);
}
__device__ inline float bf2f(unsigned short h) {
    return __builtin_bit_cast(float, (unsigned)h << 16);
}

// async 16B global->LDS (zero VGPR data path; HW adds lane*16 to the LDS base)
__device__ inline void gload16(const void* g, void* l) {
    __builtin_amdgcn_global_load_lds(
        (const __attribute__((address_space(1))) unsigned int*)g,
        (__attribute__((address_space(3))) unsigned int*)l, 16, 0, 0);
}

// ---- shared tofeat body: convert elem-groups [h*HELEM, h*HELEM+HELEM) ----
__device__ inline void tofeat_body(int half, int blk, int t,
                                   const float* __restrict__ in,
                                   unsigned short* __restrict__ outb,
                                   unsigned char* __restrict__ out8) {
    const size_t local = (size_t)blk * 512 + t;
    if (local >= HELEM) return;
    const size_t i = (size_t)half * HELEM + local;
    const float4 a = *(const float4*)&in[i * 8];
    const float4 b = *(const float4*)&in[i * 8 + 4];
    unsigned short o[8] = {f2bf(a.x), f2bf(a.y), f2bf(a.z), f2bf(a.w),
                           f2bf(b.x), f2bf(b.y), f2bf(b.z), f2bf(b.w)};
    *(bf16x8*)&outb[i * 8] = *(bf16x8*)o;
    unsigned e0 = 0, e1 = 0;
    e0 = __builtin_amdgcn_cvt_pk_fp8_f32(a.x, a.y, e0, false);
    e0 = __builtin_amdgcn_cvt_pk_fp8_f32(a.z, a.w, e0, true);
    e1 = __builtin_amdgcn_cvt_pk_fp8_f32(b.x, b.y, e1, false);
    e1 = __builtin_amdgcn_cvt_pk_fp8_f32(b.z, b.w, e1, true);
    uint2 p = {e0, e1};
    *(uint2*)&out8[i * 8] = p;
}

// ---------------- launch 1: binning + tofeat(half 0) + prepw ----------------
// pairs entry: (local_dst << 17) | src   (src < 2^17, local < 2^8)
__global__ __launch_bounds__(512) void fusedA2(const int* __restrict__ src,
                                               const int* __restrict__ dst,
                                               int* __restrict__ gcur,
                                               int* __restrict__ pairs,
                                               const float* __restrict__ in,
                                               unsigned short* __restrict__ outb,
                                               unsigned char* __restrict__ out8,
                                               const float* __restrict__ Wl1,
                                               const float* __restrict__ Wr1,
                                               const float* __restrict__ Wl2,
                                               const float* __restrict__ Wr2,
                                               unsigned short* __restrict__ wsb) {
    __shared__ int hist[BK];
    __shared__ int gbase[BK];
    __shared__ int lcur[BK];
    const int t = threadIdx.x;

    if (blockIdx.x >= NAB + TFH) {
        // ---- prepw part ----
        const int tid = (blockIdx.x - NAB - TFH) * 512 + t;   // 8192 total
        const int mat = tid >> 11;
        const int ko  = (tid >> 7) & 15;
        const int j   = tid & 127;
        const float* W = (mat == 0) ? Wl1 : (mat == 1) ? Wr1 : (mat == 2) ? Wl2 : Wr2;
        const float4 w0 = *(const float4*)&W[(size_t)j * DD + ko * 8];
        const float4 w1 = *(const float4*)&W[(size_t)j * DD + ko * 8 + 4];
        unsigned short o[8] = {f2bf(w0.x), f2bf(w0.y), f2bf(w0.z), f2bf(w0.w),
                               f2bf(w1.x), f2bf(w1.y), f2bf(w1.z), f2bf(w1.w)};
        *(bf16x8*)&wsb[(size_t)tid * 8] = *(bf16x8*)o;
        return;
    }
    if (blockIdx.x >= NAB) {
        tofeat_body(0, blockIdx.x - NAB, t, in, outb, out8);
        return;
    }

    // ---- binning part ----
    const int e0 = blockIdx.x * EPB;
    int dcache[16];
    #pragma unroll
    for (int k = 0; k < 16; ++k) {
        const int e = e0 + t + k * 512;
        dcache[k] = (e < NE) ? dst[e] : -1;
    }

    for (int i = t; i < BK; i += 512) hist[i] = 0;
    __syncthreads();
    #pragma unroll
    for (int k = 0; k < 16; ++k)
        if (dcache[k] >= 0) atomicAdd(&hist[dcache[k] >> ASHIFT], 1);
    __syncthreads();
    for (int i = t; i < BK; i += 512) {
        int c = hist[i];
        gbase[i] = i * BCAP + (c ? atomicAdd(&gcur[i], c) : 0);  // block-private run
        lcur[i] = 0;
    }
    __syncthreads();
    #pragma unroll
    for (int k = 0; k < 16; ++k) {
        const int e = e0 + t + k * 512;
        const int d = dcache[k];
        if (d >= 0) {
            const int b = d >> ASHIFT;
            const int r = atomicAdd(&lcur[b], 1);
            pairs[gbase[b] + r] = ((d & (NSPAN - 1)) << 17) | src[e];
        }
    }
}

// ---------------- launch 2: bucketB (CSR finalize) + tofeat(half 1) --------
__global__ __launch_bounds__(512) void fusedB2(const int* __restrict__ pairs,
                                               const int* __restrict__ gcur,
                                               int* __restrict__ cnt,
                                               int* __restrict__ rowoff,
                                               int* __restrict__ csr,
                                               const float* __restrict__ in,
                                               unsigned short* __restrict__ outb,
                                               unsigned char* __restrict__ out8) {
    __shared__ int bs[512];
    __shared__ int hist[NSPAN];
    __shared__ int scanbuf[NSPAN];
    const int t = threadIdx.x;

    if (blockIdx.x >= BK) {
        tofeat_body(1, blockIdx.x - BK, t, in, outb, out8);
        return;
    }

    const int b = blockIdx.x;
    int v = (t < BK) ? gcur[t] : 0;
    bs[t] = v;
    __syncthreads();
    #pragma unroll
    for (int d = 1; d < 512; d <<= 1) {
        int u = (t >= d) ? bs[t - d] : 0;
        __syncthreads();
        bs[t] += u;
        __syncthreads();
    }
    const int sz   = gcur[b];
    const int base = bs[b] - sz;          // exclusive prefix

    const int n0    = b << ASHIFT;
    const int nodeN = min(NSPAN, NN - n0);
    const int* ep   = &pairs[(size_t)b * BCAP];

    for (int i = t; i < NSPAN; i += 512) hist[i] = 0;
    __syncthreads();
    for (int i = t; i < sz; i += 512) atomicAdd(&hist[((unsigned)ep[i]) >> 17], 1);
    __syncthreads();
    for (int i = t; i < nodeN; i += 512) cnt[n0 + i] = hist[i];
    for (int i = t; i < NSPAN; i += 512) scanbuf[i] = hist[i];
    __syncthreads();
    #pragma unroll
    for (int d = 1; d < NSPAN; d <<= 1) {
        int v0 = (t >= d && t < NSPAN) ? scanbuf[t - d] : 0;
        __syncthreads();
        if (t < NSPAN) scanbuf[t] += v0;
        __syncthreads();
    }
    for (int i = t; i < NSPAN; i += 512) {
        int excl = scanbuf[i] - hist[i];
        if (i < nodeN) rowoff[n0 + i] = base + excl;
        hist[i] = excl;                     // reuse as cursor
    }
    if (b == BK - 1 && t == 0) rowoff[NN] = NE;
    __syncthreads();
    for (int i = t; i < sz; i += 512) {
        int p = ep[i];
        int r = atomicAdd(&hist[((unsigned)p) >> 17], 1);
        csr[base + r] = p & 0x1FFFF;        // block-private ~16KB window
    }
}

// ---------------- gather mean (fp8 in, bf16 out, fp32 accum) ----------------
// 16 lanes per node, 8 fp8 (8B) per lane; 16-edge unroll: mean degree is 16,
// so the modal node completes in ONE batch of 16 outstanding loads per lane
// (round-11 counters: latency-bound, nothing saturated -> raise per-lane MLP).
// VGPR demand ~70 < the 85-reg/6-wave step -> no spill (round-9 lesson:
// spills happen when demand exceeds the step, here it doesn't).
// a0/a1 parity alternation identical to the 8-deep version -> bitwise-same.
__device__ inline void accum8(float* a, uint2 u) {
    f32x2 p;
    p = __builtin_amdgcn_cvt_pk_f32_fp8(u.x, false); a[0] += p.x; a[1] += p.y;
    p = __builtin_amdgcn_cvt_pk_f32_fp8(u.x, true);  a[2] += p.x; a[3] += p.y;
    p = __builtin_amdgcn_cvt_pk_f32_fp8(u.y, false); a[4] += p.x; a[5] += p.y;
    p = __builtin_amdgcn_cvt_pk_f32_fp8(u.y, true);  a[6] += p.x; a[7] += p.y;
}

__global__ __launch_bounds__(256) void gather_fp8(const unsigned char* __restrict__ feat,
                                                  const int* __restrict__ rowoff,
                                                  const int* __restrict__ csr,
                                                  const int* __restrict__ cnt,
                                                  unsigned short* __restrict__ mean) {
    const int node = blockIdx.x * 16 + (threadIdx.x >> 4);
    const int l8 = (threadIdx.x & 15) * 8;
    const int beg = rowoff[node], end = rowoff[node + 1];
    float a0[8] = {0, 0, 0, 0, 0, 0, 0, 0};
    float a1[8] = {0, 0, 0, 0, 0, 0, 0, 0};
    int j = beg;
    for (; j + 15 < end; j += 16) {
        int s0 = csr[j],      s1 = csr[j + 1],  s2 = csr[j + 2],  s3 = csr[j + 3];
        int s4 = csr[j + 4],  s5 = csr[j + 5],  s6 = csr[j + 6],  s7 = csr[j + 7];
        int s8 = csr[j + 8],  s9 = csr[j + 9],  sa = csr[j + 10], sb = csr[j + 11];
        int sc = csr[j + 12], sd = csr[j + 13], se = csr[j + 14], sf = csr[j + 15];
        uint2 u0 = *(const uint2*)&feat[(size_t)s0 * DD + l8];
        uint2 u1 = *(const uint2*)&feat[(size_t)s1 * DD + l8];
        uint2 u2 = *(const uint2*)&feat[(size_t)s2 * DD + l8];
        uint2 u3 = *(const uint2*)&feat[(size_t)s3 * DD + l8];
        uint2 u4 = *(const uint2*)&feat[(size_t)s4 * DD + l8];
        uint2 u5 = *(const uint2*)&feat[(size_t)s5 * DD + l8];
        uint2 u6 = *(const uint2*)&feat[(size_t)s6 * DD + l8];
        uint2 u7 = *(const uint2*)&feat[(size_t)s7 * DD + l8];
        uint2 u8 = *(const uint2*)&feat[(size_t)s8 * DD + l8];
        uint2 u9 = *(const uint2*)&feat[(size_t)s9 * DD + l8];
        uint2 ua = *(const uint2*)&feat[(size_t)sa * DD + l8];
        uint2 ub = *(const uint2*)&feat[(size_t)sb * DD + l8];
        uint2 uc = *(const uint2*)&feat[(size_t)sc * DD + l8];
        uint2 ud = *(const uint2*)&feat[(size_t)sd * DD + l8];
        uint2 ue = *(const uint2*)&feat[(size_t)se * DD + l8];
        uint2 uf = *(const uint2*)&feat[(size_t)sf * DD + l8];
        accum8(a0, u0); accum8(a1, u1); accum8(a0, u2); accum8(a1, u3);
        accum8(a0, u4); accum8(a1, u5); accum8(a0, u6); accum8(a1, u7);
        accum8(a0, u8); accum8(a1, u9); accum8(a0, ua); accum8(a1, ub);
        accum8(a0, uc); accum8(a1, ud); accum8(a0, ue); accum8(a1, uf);
    }
    for (; j + 7 < end; j += 8) {
        int s0 = csr[j],     s1 = csr[j + 1], s2 = csr[j + 2], s3 = csr[j + 3];
        int s4 = csr[j + 4], s5 = csr[j + 5], s6 = csr[j + 6], s7 = csr[j + 7];
        uint2 u0 = *(const uint2*)&feat[(size_t)s0 * DD + l8];
        uint2 u1 = *(const uint2*)&feat[(size_t)s1 * DD + l8];
        uint2 u2 = *(const uint2*)&feat[(size_t)s2 * DD + l8];
        uint2 u3 = *(const uint2*)&feat[(size_t)s3 * DD + l8];
        uint2 u4 = *(const uint2*)&feat[(size_t)s4 * DD + l8];
        uint2 u5 = *(const uint2*)&feat[(size_t)s5 * DD + l8];
        uint2 u6 = *(const uint2*)&feat[(size_t)s6 * DD + l8];
        uint2 u7 = *(const uint2*)&feat[(size_t)s7 * DD + l8];
        accum8(a0, u0); accum8(a1, u1); accum8(a0, u2); accum8(a1, u3);
        accum8(a0, u4); accum8(a1, u5); accum8(a0, u6); accum8(a1, u7);
    }
    for (; j + 3 < end; j += 4) {
        int s0 = csr[j], s1 = csr[j + 1], s2 = csr[j + 2], s3 = csr[j + 3];
        uint2 u0 = *(const uint2*)&feat[(size_t)s0 * DD + l8];
        uint2 u1 = *(const uint2*)&feat[(size_t)s1 * DD + l8];
        uint2 u2 = *(const uint2*)&feat[(size_t)s2 * DD + l8];
        uint2 u3 = *(const uint2*)&feat[(size_t)s3 * DD + l8];
        accum8(a0, u0); accum8(a1, u1); accum8(a0, u2); accum8(a1, u3);
    }
    for (; j < end; ++j) {
        int s0 = csr[j];
        uint2 u0 = *(const uint2*)&feat[(size_t)s0 * DD + l8];
        accum8(a0, u0);
    }
    const float inv = 1.0f / fmaxf((float)cnt[node], 1.0f);
    unsigned short o[8];
    #pragma unroll
    for (int i = 0; i < 8; ++i) o[i] = f2bf((a0[i] + a1[i]) * inv);
    *(bf16x8*)&mean[(size_t)node * DD + l8] = *(bf16x8*)o;
}

// ---------------- combine via MFMA, LDS-staged A (m97 pattern) ----------------
// 512 thr = 8 waves; wave wv owns output column-tile jt = wv -> bfr is only
// 8 frags (32 VGPR), keeping the live set under the allocator's 85-reg
// occupancy step. A-tiles double-buffered in LDS via global_load_lds
// (zero VGPR data path): stage tile t+1 while MFMA-ing tile t.
__global__ __launch_bounds__(512, 3) void combine_lds(
    const unsigned short* __restrict__ meanp, const unsigned short* __restrict__ selfp,
    const unsigned short* __restrict__ wsb,   // pre-converted bf16 fragments (64KB)
    const float* __restrict__ bias, void* __restrict__ outp,
    unsigned char* __restrict__ out8,         // optional fp8 copy (layer-1 h)
    int out_bf16, int do_relu)
{
    __shared__ unsigned short sAB[2][2][2048];   // [buf][mean/self][16 rows x 128] 16KB
    const int t = threadIdx.x;
    const int wv = t >> 6, lane = t & 63;
    const int m = lane & 15;
    const int q = lane >> 4;
    const int j0 = wv;                        // this wave's single jt column

    // staging role of this wave: region (mean/self) + kq slice
    const int sreg = wv >> 2;                 // 0 = mean, 1 = self
    const int skq  = wv & 3;
    const int soff = m * 256 + skq * 64 + q * 16;   // per-lane source byte offset

    // register-resident B fragments: [half][kq] — 8 frags = 32 VGPR
    bf16x8 bfr[2][4];
    #pragma unroll
    for (int h = 0; h < 2; ++h)
        #pragma unroll
        for (int kq = 0; kq < 4; ++kq)
            bfr[h][kq] = *(const bf16x8*)
                &wsb[((size_t)((h * 16 + kq * 4 + q) * 128) + j0 * 16 + m) * 8];

    const float bv = bias[j0 * 16 + m];

    const int NT = NN / 16;

#define STAGE(BUF, TL)                                                        \
    {                                                                         \
        const char* base_ = sreg ? (const char*)selfp : (const char*)meanp;   \
        gload16(base_ + (size_t)(TL) * 4096 + soff,                           \
                (char*)&sAB[BUF][sreg][0] + skq * 1024);                      \
    }

    int tile = blockIdx.x;
    STAGE(0, tile)
    __syncthreads();                           // drains vmcnt(0): buf0 ready
    int cur = 0;

    for (; tile < NT; tile += CGRID) {
        const int nxt = tile + CGRID;
        if (nxt < NT) STAGE(cur ^ 1, nxt)      // async prefetch next tile

        f32x4 acc = (f32x4){0.f, 0.f, 0.f, 0.f};
        #pragma unroll
        for (int kq = 0; kq < 4; ++kq) {
            const bf16x8 am = *(const bf16x8*)&sAB[cur][0][kq * 512 + lane * 8];
            const bf16x8 as = *(const bf16x8*)&sAB[cur][1][kq * 512 + lane * 8];
            acc = __builtin_amdgcn_mfma_f32_16x16x32_bf16(am, bfr[0][kq], acc, 0, 0, 0);
            acc = __builtin_amdgcn_mfma_f32_16x16x32_bf16(as, bfr[1][kq], acc, 0, 0, 0);
        }

        const int col = j0 * 16 + m;
        #pragma unroll
        for (int r = 0; r < 4; ++r) {
            const size_t row = (size_t)tile * 16 + q * 4 + r;
            float v = acc[r] + bv;
            if (do_relu) v = fmaxf(v, 0.0f);
            if (out_bf16)
                ((unsigned short*)outp)[row * DD + col] = f2bf(v);
            else
                ((float*)outp)[row * DD + col] = v;
            if (out8) {
                unsigned p = __builtin_amdgcn_cvt_pk_fp8_f32(v, v, 0u, false);
                out8[row * DD + col] = (unsigned char)p;
            }
        }

        __syncthreads();                       // drains next-tile loads; all
        cur ^= 1;                              // reads of cur complete
    }
#undef STAGE
}

extern "C" void kernel_launch(void* const* d_in, const int* in_sizes, int n_in,
                              void* d_out, int out_size, void* d_ws, size_t ws_size,
                              hipStream_t stream) {
    const float* x   = (const float*)d_in[0];
    const int*   ei  = (const int*)d_in[1];
    const float* Wl1 = (const float*)d_in[2];
    const float* Wr1 = (const float*)d_in[3];
    const float* b1  = (const float*)d_in[4];
    const float* Wl2 = (const float*)d_in[5];
    const float* Wr2 = (const float*)d_in[6];
    const float* b2  = (const float*)d_in[7];
    const int* src = ei;
    const int* dst = ei + NE;
    float* out = (float*)d_out;

    // workspace layout
    unsigned short* xb   = (unsigned short*)d_ws;              // NN*DD bf16 (25.6MB)
    unsigned short* mean = xb + (size_t)NN * DD;               // NN*DD bf16 (25.6MB)
    unsigned short* h    = mean + (size_t)NN * DD;             // NN*DD bf16 (25.6MB)
    unsigned char*  x8   = (unsigned char*)(h + (size_t)NN * DD); // NN*DD fp8 (12.8MB)
    unsigned char*  h8   = x8 + (size_t)NN * DD;               // NN*DD fp8 (12.8MB)
    int*  pairs  = (int*)(h8 + (size_t)NN * DD);               // BK*BCAP (7.2MB)
    int*  gcur   = pairs + (size_t)BK * BCAP;                  // BK
    int*  cnt    = gcur + BK;                                  // NN
    int*  rowoff = cnt + NN;                                   // NN+1
    int*  csr    = rowoff + NN + 1;                            // NE (6.4MB)
    uintptr_t wp = ((uintptr_t)(csr + NE) + 255) & ~(uintptr_t)255;
    unsigned short* wsb = (unsigned short*)wp;                 // 2 layers * 32768 bf16 (128KB)

    hipMemsetAsync(gcur, 0, BK * sizeof(int), stream);
    fusedA2<<<NAB + TFH + PWB, 512, 0, stream>>>(src, dst, gcur, pairs,
                                                 x, xb, x8,
                                                 Wl1, Wr1, Wl2, Wr2, wsb);
    fusedB2<<<BK + TFH, 512, 0, stream>>>(pairs, gcur, cnt, rowoff, csr, x, xb, x8);

    gather_fp8<<<NN / 16, 256, 0, stream>>>(x8, rowoff, csr, cnt, mean);
    combine_lds<<<CGRID, 512, 0, stream>>>(mean, xb, wsb, b1, h, h8, 1, 1);

    gather_fp8<<<NN / 16, 256, 0, stream>>>(h8, rowoff, csr, cnt, mean);
    combine_lds<<<CGRID, 512, 0, stream>>>(mean, h, wsb + 32768, b2, out, nullptr, 0, 0);
}

// Round 13
// 246.907 us; speedup vs baseline: 1.1347x; 1.0976x over previous
//
#include <hip/hip_runtime.h>
#include <hip/hip_bf16.h>

#define NN 100000
#define NE 1600000
#define DD 128

#define ASHIFT 8            // bucket = dst >> 8 (256-node span)
#define NSPAN  256
#define BK     391          // ceil(100000/256)
#define BCAP   4608         // per-bucket capacity (mean 4092, +8 sigma)
#define EPB    8192         // edges per binning block (196 blocks -> low gcur contention)
#define NAB    196          // ceil(NE/EPB)
#define TFH    1563         // tofeat blocks per half: ceil(800000/512)
#define HELEM  800000       // elem-groups (of 8) per tofeat half
#define PWB    16           // prepw blocks at 512 thr (8192 threads)
#define CGRID  1024         // combine grid (512-thread blocks)

typedef __attribute__((ext_vector_type(8))) short bf16x8;
typedef __attribute__((ext_vector_type(4))) float f32x4;
typedef __attribute__((ext_vector_type(2))) float f32x2;

__device__ inline unsigned short f2bf(float f) {          // RNE float->bf16
    unsigned u = __builtin_bit_cast(unsigned, f);
    u += 0x7fff + ((u >> 16) & 1);
    return (unsigned short)(u >> 16);
}
__device__ inline float bf2f(unsigned short h) {
    return __builtin_bit_cast(float, (unsigned)h << 16);
}

// async 16B global->LDS (zero VGPR data path; HW adds lane*16 to the LDS base)
__device__ inline void gload16(const void* g, void* l) {
    __builtin_amdgcn_global_load_lds(
        (const __attribute__((address_space(1))) unsigned int*)g,
        (__attribute__((address_space(3))) unsigned int*)l, 16, 0, 0);
}

// ---- shared tofeat body: convert elem-groups [h*HELEM, h*HELEM+HELEM) ----
__device__ inline void tofeat_body(int half, int blk, int t,
                                   const float* __restrict__ in,
                                   unsigned short* __restrict__ outb,
                                   unsigned char* __restrict__ out8) {
    const size_t local = (size_t)blk * 512 + t;
    if (local >= HELEM) return;
    const size_t i = (size_t)half * HELEM + local;
    const float4 a = *(const float4*)&in[i * 8];
    const float4 b = *(const float4*)&in[i * 8 + 4];
    unsigned short o[8] = {f2bf(a.x), f2bf(a.y), f2bf(a.z), f2bf(a.w),
                           f2bf(b.x), f2bf(b.y), f2bf(b.z), f2bf(b.w)};
    *(bf16x8*)&outb[i * 8] = *(bf16x8*)o;
    unsigned e0 = 0, e1 = 0;
    e0 = __builtin_amdgcn_cvt_pk_fp8_f32(a.x, a.y, e0, false);
    e0 = __builtin_amdgcn_cvt_pk_fp8_f32(a.z, a.w, e0, true);
    e1 = __builtin_amdgcn_cvt_pk_fp8_f32(b.x, b.y, e1, false);
    e1 = __builtin_amdgcn_cvt_pk_fp8_f32(b.z, b.w, e1, true);
    uint2 p = {e0, e1};
    *(uint2*)&out8[i * 8] = p;
}

// ---------------- launch 1: binning + tofeat(half 0) + prepw ----------------
// pairs entry: (local_dst << 17) | src   (src < 2^17, local < 2^8)
// Both dst AND src register-cached across the passes (32 VGPR) — no global
// re-reads inside the LDS-atomic scatter loop.
__global__ __launch_bounds__(512) void fusedA2(const int* __restrict__ src,
                                               const int* __restrict__ dst,
                                               int* __restrict__ gcur,
                                               int* __restrict__ pairs,
                                               const float* __restrict__ in,
                                               unsigned short* __restrict__ outb,
                                               unsigned char* __restrict__ out8,
                                               const float* __restrict__ Wl1,
                                               const float* __restrict__ Wr1,
                                               const float* __restrict__ Wl2,
                                               const float* __restrict__ Wr2,
                                               unsigned short* __restrict__ wsb) {
    __shared__ int hist[BK];
    __shared__ int gbase[BK];
    __shared__ int lcur[BK];
    const int t = threadIdx.x;

    if (blockIdx.x >= NAB + TFH) {
        // ---- prepw part ----
        const int tid = (blockIdx.x - NAB - TFH) * 512 + t;   // 8192 total
        const int mat = tid >> 11;
        const int ko  = (tid >> 7) & 15;
        const int j   = tid & 127;
        const float* W = (mat == 0) ? Wl1 : (mat == 1) ? Wr1 : (mat == 2) ? Wl2 : Wr2;
        const float4 w0 = *(const float4*)&W[(size_t)j * DD + ko * 8];
        const float4 w1 = *(const float4*)&W[(size_t)j * DD + ko * 8 + 4];
        unsigned short o[8] = {f2bf(w0.x), f2bf(w0.y), f2bf(w0.z), f2bf(w0.w),
                               f2bf(w1.x), f2bf(w1.y), f2bf(w1.z), f2bf(w1.w)};
        *(bf16x8*)&wsb[(size_t)tid * 8] = *(bf16x8*)o;
        return;
    }
    if (blockIdx.x >= NAB) {
        tofeat_body(0, blockIdx.x - NAB, t, in, outb, out8);
        return;
    }

    // ---- binning part ----
    const int e0 = blockIdx.x * EPB;
    int dcache[16];
    int scache[16];
    #pragma unroll
    for (int k = 0; k < 16; ++k) {
        const int e = e0 + t + k * 512;
        const bool v = e < NE;
        dcache[k] = v ? dst[e] : -1;
        scache[k] = v ? src[e] : 0;
    }

    for (int i = t; i < BK; i += 512) hist[i] = 0;
    __syncthreads();
    #pragma unroll
    for (int k = 0; k < 16; ++k)
        if (dcache[k] >= 0) atomicAdd(&hist[dcache[k] >> ASHIFT], 1);
    __syncthreads();
    for (int i = t; i < BK; i += 512) {
        int c = hist[i];
        gbase[i] = i * BCAP + (c ? atomicAdd(&gcur[i], c) : 0);  // block-private run
        lcur[i] = 0;
    }
    __syncthreads();
    #pragma unroll
    for (int k = 0; k < 16; ++k) {
        const int d = dcache[k];
        if (d >= 0) {
            const int b = d >> ASHIFT;
            const int r = atomicAdd(&lcur[b], 1);
            pairs[gbase[b] + r] = ((d & (NSPAN - 1)) << 17) | scache[k];
        }
    }
}

// ---------------- launch 2: bucketB (CSR finalize) + tofeat(half 1) --------
__global__ __launch_bounds__(512) void fusedB2(const int* __restrict__ pairs,
                                               const int* __restrict__ gcur,
                                               int* __restrict__ cnt,
                                               int* __restrict__ rowoff,
                                               int* __restrict__ csr,
                                               const float* __restrict__ in,
                                               unsigned short* __restrict__ outb,
                                               unsigned char* __restrict__ out8) {
    __shared__ int bs[512];
    __shared__ int hist[NSPAN];
    __shared__ int scanbuf[NSPAN];
    const int t = threadIdx.x;

    if (blockIdx.x >= BK) {
        tofeat_body(1, blockIdx.x - BK, t, in, outb, out8);
        return;
    }

    const int b = blockIdx.x;
    int v = (t < BK) ? gcur[t] : 0;
    bs[t] = v;
    __syncthreads();
    #pragma unroll
    for (int d = 1; d < 512; d <<= 1) {
        int u = (t >= d) ? bs[t - d] : 0;
        __syncthreads();
        bs[t] += u;
        __syncthreads();
    }
    const int sz   = gcur[b];
    const int base = bs[b] - sz;          // exclusive prefix

    const int n0    = b << ASHIFT;
    const int nodeN = min(NSPAN, NN - n0);
    const int* ep   = &pairs[(size_t)b * BCAP];

    for (int i = t; i < NSPAN; i += 512) hist[i] = 0;
    __syncthreads();
    for (int i = t; i < sz; i += 512) atomicAdd(&hist[((unsigned)ep[i]) >> 17], 1);
    __syncthreads();
    for (int i = t; i < nodeN; i += 512) cnt[n0 + i] = hist[i];
    for (int i = t; i < NSPAN; i += 512) scanbuf[i] = hist[i];
    __syncthreads();
    #pragma unroll
    for (int d = 1; d < NSPAN; d <<= 1) {
        int v0 = (t >= d && t < NSPAN) ? scanbuf[t - d] : 0;
        __syncthreads();
        if (t < NSPAN) scanbuf[t] += v0;
        __syncthreads();
    }
    for (int i = t; i < NSPAN; i += 512) {
        int excl = scanbuf[i] - hist[i];
        if (i < nodeN) rowoff[n0 + i] = base + excl;
        hist[i] = excl;                     // reuse as cursor
    }
    if (b == BK - 1 && t == 0) rowoff[NN] = NE;
    __syncthreads();
    for (int i = t; i < sz; i += 512) {
        int p = ep[i];
        int r = atomicAdd(&hist[((unsigned)p) >> 17], 1);
        csr[base + r] = p & 0x1FFFF;        // block-private ~16KB window
    }
}

// ---------------- gather mean (fp8 in, bf16 out, fp32 accum) ----------------
// 16 lanes per node, 8 fp8 (8B) per lane; 8-edge unroll, 2 acc chains.
// NOTE (round-12 post-mortem): 8-deep is the measured optimum. 16-deep
// REGRESSED (43.5us, FETCH 80MB vs ~12.8MB working set): doubling outstanding
// random lines thrashes the XCD L2s and loses the row-reuse hits. 4->8 won
// (round 5); 8->16 lost. Do not deepen further.
__device__ inline void accum8(float* a, uint2 u) {
    f32x2 p;
    p = __builtin_amdgcn_cvt_pk_f32_fp8(u.x, false); a[0] += p.x; a[1] += p.y;
    p = __builtin_amdgcn_cvt_pk_f32_fp8(u.x, true);  a[2] += p.x; a[3] += p.y;
    p = __builtin_amdgcn_cvt_pk_f32_fp8(u.y, false); a[4] += p.x; a[5] += p.y;
    p = __builtin_amdgcn_cvt_pk_f32_fp8(u.y, true);  a[6] += p.x; a[7] += p.y;
}

__global__ __launch_bounds__(256) void gather_fp8(const unsigned char* __restrict__ feat,
                                                  const int* __restrict__ rowoff,
                                                  const int* __restrict__ csr,
                                                  const int* __restrict__ cnt,
                                                  unsigned short* __restrict__ mean) {
    const int node = blockIdx.x * 16 + (threadIdx.x >> 4);
    const int l8 = (threadIdx.x & 15) * 8;
    const int beg = rowoff[node], end = rowoff[node + 1];
    float a0[8] = {0, 0, 0, 0, 0, 0, 0, 0};
    float a1[8] = {0, 0, 0, 0, 0, 0, 0, 0};
    int j = beg;
    for (; j + 7 < end; j += 8) {
        int s0 = csr[j],     s1 = csr[j + 1], s2 = csr[j + 2], s3 = csr[j + 3];
        int s4 = csr[j + 4], s5 = csr[j + 5], s6 = csr[j + 6], s7 = csr[j + 7];
        uint2 u0 = *(const uint2*)&feat[(size_t)s0 * DD + l8];
        uint2 u1 = *(const uint2*)&feat[(size_t)s1 * DD + l8];
        uint2 u2 = *(const uint2*)&feat[(size_t)s2 * DD + l8];
        uint2 u3 = *(const uint2*)&feat[(size_t)s3 * DD + l8];
        uint2 u4 = *(const uint2*)&feat[(size_t)s4 * DD + l8];
        uint2 u5 = *(const uint2*)&feat[(size_t)s5 * DD + l8];
        uint2 u6 = *(const uint2*)&feat[(size_t)s6 * DD + l8];
        uint2 u7 = *(const uint2*)&feat[(size_t)s7 * DD + l8];
        accum8(a0, u0); accum8(a1, u1); accum8(a0, u2); accum8(a1, u3);
        accum8(a0, u4); accum8(a1, u5); accum8(a0, u6); accum8(a1, u7);
    }
    for (; j + 3 < end; j += 4) {
        int s0 = csr[j], s1 = csr[j + 1], s2 = csr[j + 2], s3 = csr[j + 3];
        uint2 u0 = *(const uint2*)&feat[(size_t)s0 * DD + l8];
        uint2 u1 = *(const uint2*)&feat[(size_t)s1 * DD + l8];
        uint2 u2 = *(const uint2*)&feat[(size_t)s2 * DD + l8];
        uint2 u3 = *(const uint2*)&feat[(size_t)s3 * DD + l8];
        accum8(a0, u0); accum8(a1, u1); accum8(a0, u2); accum8(a1, u3);
    }
    for (; j < end; ++j) {
        int s0 = csr[j];
        uint2 u0 = *(const uint2*)&feat[(size_t)s0 * DD + l8];
        accum8(a0, u0);
    }
    const float inv = 1.0f / fmaxf((float)cnt[node], 1.0f);
    unsigned short o[8];
    #pragma unroll
    for (int i = 0; i < 8; ++i) o[i] = f2bf((a0[i] + a1[i]) * inv);
    *(bf16x8*)&mean[(size_t)node * DD + l8] = *(bf16x8*)o;
}

// ---------------- combine via MFMA, LDS-staged A (m97 pattern) ----------------
// 512 thr = 8 waves; wave wv owns output column-tile jt = wv -> bfr is only
// 8 frags (32 VGPR), keeping the live set under the allocator's 85-reg
// occupancy step. A-tiles double-buffered in LDS via global_load_lds
// (zero VGPR data path): stage tile t+1 while MFMA-ing tile t.
__global__ __launch_bounds__(512, 3) void combine_lds(
    const unsigned short* __restrict__ meanp, const unsigned short* __restrict__ selfp,
    const unsigned short* __restrict__ wsb,   // pre-converted bf16 fragments (64KB)
    const float* __restrict__ bias, void* __restrict__ outp,
    unsigned char* __restrict__ out8,         // optional fp8 copy (layer-1 h)
    int out_bf16, int do_relu)
{
    __shared__ unsigned short sAB[2][2][2048];   // [buf][mean/self][16 rows x 128] 16KB
    const int t = threadIdx.x;
    const int wv = t >> 6, lane = t & 63;
    const int m = lane & 15;
    const int q = lane >> 4;
    const int j0 = wv;                        // this wave's single jt column

    // staging role of this wave: region (mean/self) + kq slice
    const int sreg = wv >> 2;                 // 0 = mean, 1 = self
    const int skq  = wv & 3;
    const int soff = m * 256 + skq * 64 + q * 16;   // per-lane source byte offset

    // register-resident B fragments: [half][kq] — 8 frags = 32 VGPR
    bf16x8 bfr[2][4];
    #pragma unroll
    for (int h = 0; h < 2; ++h)
        #pragma unroll
        for (int kq = 0; kq < 4; ++kq)
            bfr[h][kq] = *(const bf16x8*)
                &wsb[((size_t)((h * 16 + kq * 4 + q) * 128) + j0 * 16 + m) * 8];

    const float bv = bias[j0 * 16 + m];

    const int NT = NN / 16;

#define STAGE(BUF, TL)                                                        \
    {                                                                         \
        const char* base_ = sreg ? (const char*)selfp : (const char*)meanp;   \
        gload16(base_ + (size_t)(TL) * 4096 + soff,                           \
                (char*)&sAB[BUF][sreg][0] + skq * 1024);                      \
    }

    int tile = blockIdx.x;
    STAGE(0, tile)
    __syncthreads();                           // drains vmcnt(0): buf0 ready
    int cur = 0;

    for (; tile < NT; tile += CGRID) {
        const int nxt = tile + CGRID;
        if (nxt < NT) STAGE(cur ^ 1, nxt)      // async prefetch next tile

        f32x4 acc = (f32x4){0.f, 0.f, 0.f, 0.f};
        #pragma unroll
        for (int kq = 0; kq < 4; ++kq) {
            const bf16x8 am = *(const bf16x8*)&sAB[cur][0][kq * 512 + lane * 8];
            const bf16x8 as = *(const bf16x8*)&sAB[cur][1][kq * 512 + lane * 8];
            acc = __builtin_amdgcn_mfma_f32_16x16x32_bf16(am, bfr[0][kq], acc, 0, 0, 0);
            acc = __builtin_amdgcn_mfma_f32_16x16x32_bf16(as, bfr[1][kq], acc, 0, 0, 0);
        }

        const int col = j0 * 16 + m;
        #pragma unroll
        for (int r = 0; r < 4; ++r) {
            const size_t row = (size_t)tile * 16 + q * 4 + r;
            float v = acc[r] + bv;
            if (do_relu) v = fmaxf(v, 0.0f);
            if (out_bf16)
                ((unsigned short*)outp)[row * DD + col] = f2bf(v);
            else
                ((float*)outp)[row * DD + col] = v;
            if (out8) {
                unsigned p = __builtin_amdgcn_cvt_pk_fp8_f32(v, v, 0u, false);
                out8[row * DD + col] = (unsigned char)p;
            }
        }

        __syncthreads();                       // drains next-tile loads; all
        cur ^= 1;                              // reads of cur complete
    }
#undef STAGE
}

extern "C" void kernel_launch(void* const* d_in, const int* in_sizes, int n_in,
                              void* d_out, int out_size, void* d_ws, size_t ws_size,
                              hipStream_t stream) {
    const float* x   = (const float*)d_in[0];
    const int*   ei  = (const int*)d_in[1];
    const float* Wl1 = (const float*)d_in[2];
    const float* Wr1 = (const float*)d_in[3];
    const float* b1  = (const float*)d_in[4];
    const float* Wl2 = (const float*)d_in[5];
    const float* Wr2 = (const float*)d_in[6];
    const float* b2  = (const float*)d_in[7];
    const int* src = ei;
    const int* dst = ei + NE;
    float* out = (float*)d_out;

    // workspace layout
    unsigned short* xb   = (unsigned short*)d_ws;              // NN*DD bf16 (25.6MB)
    unsigned short* mean = xb + (size_t)NN * DD;               // NN*DD bf16 (25.6MB)
    unsigned short* h    = mean + (size_t)NN * DD;             // NN*DD bf16 (25.6MB)
    unsigned char*  x8   = (unsigned char*)(h + (size_t)NN * DD); // NN*DD fp8 (12.8MB)
    unsigned char*  h8   = x8 + (size_t)NN * DD;               // NN*DD fp8 (12.8MB)
    int*  pairs  = (int*)(h8 + (size_t)NN * DD);               // BK*BCAP (7.2MB)
    int*  gcur   = pairs + (size_t)BK * BCAP;                  // BK
    int*  cnt    = gcur + BK;                                  // NN
    int*  rowoff = cnt + NN;                                   // NN+1
    int*  csr    = rowoff + NN + 1;                            // NE (6.4MB)
    uintptr_t wp = ((uintptr_t)(csr + NE) + 255) & ~(uintptr_t)255;
    unsigned short* wsb = (unsigned short*)wp;                 // 2 layers * 32768 bf16 (128KB)

    hipMemsetAsync(gcur, 0, BK * sizeof(int), stream);
    fusedA2<<<NAB + TFH + PWB, 512, 0, stream>>>(src, dst, gcur, pairs,
                                                 x, xb, x8,
                                                 Wl1, Wr1, Wl2, Wr2, wsb);
    fusedB2<<<BK + TFH, 512, 0, stream>>>(pairs, gcur, cnt, rowoff, csr, x, xb, x8);

    gather_fp8<<<NN / 16, 256, 0, stream>>>(x8, rowoff, csr, cnt, mean);
    combine_lds<<<CGRID, 512, 0, stream>>>(mean, xb, wsb, b1, h, h8, 1, 1);

    gather_fp8<<<NN / 16, 256, 0, stream>>>(h8, rowoff, csr, cnt, mean);
    combine_lds<<<CGRID, 512, 0, stream>>>(mean, h, wsb + 32768, b2, out, nullptr, 0, 0);
}